// Round 8
// baseline (260.084 us; speedup 1.0000x reference)
//
#include <hip/hip_runtime.h>
#include <hip/hip_bf16.h>
#include <math.h>

// Problem constants
#define BATCH 8192
#define NB 9
#define NN 256
#define PMAX 8
#define HID 32
#define ZDIM 2304   // NB*NN

typedef short bf16x8 __attribute__((ext_vector_type(8)));   // 8 bf16 in 4 VGPRs
typedef float f32x4 __attribute__((ext_vector_type(4)));    // MFMA accumulator

static __device__ inline unsigned short f2bf(float f) {
    __hip_bfloat16 h = __float2bfloat16(f);
    return *reinterpret_cast<unsigned short*>(&h);
}

static __device__ inline uint4 pack8(float4 a, float4 b) {
    uint4 u;
    u.x = (unsigned)f2bf(a.x) | ((unsigned)f2bf(a.y) << 16);
    u.y = (unsigned)f2bf(a.z) | ((unsigned)f2bf(a.w) << 16);
    u.z = (unsigned)f2bf(b.x) | ((unsigned)f2bf(b.y) << 16);
    u.w = (unsigned)f2bf(b.z) | ((unsigned)f2bf(b.w) << 16);
    return u;
}

// ---------------- K0: pack weights to bf16 ------------------------------------
__global__ __launch_bounds__(256) void k_pack(
    const float* __restrict__ W, const float* __restrict__ gW1,
    unsigned short* __restrict__ Wb, unsigned short* __restrict__ WTb,
    unsigned short* __restrict__ gW1b, unsigned short* __restrict__ g1Tb) {
    int r = blockIdx.z;
    int t = threadIdx.x;
    if (r < 8) {
        __shared__ float tt[32][33];
        int i0 = blockIdx.y * 32;
        int j0 = blockIdx.x * 32;
        int tx = t & 31;
        int ty = t >> 5;
        const float* src = W + (size_t)r * 65536;
        #pragma unroll
        for (int s = 0; s < 32; s += 8) {
            float v = src[(size_t)(i0 + ty + s) * 256 + (j0 + tx)];
            tt[ty + s][tx] = v;
            Wb[(size_t)r * 65536 + (size_t)(i0 + ty + s) * 256 + (j0 + tx)] = f2bf(v);
        }
        __syncthreads();
        #pragma unroll
        for (int s = 0; s < 32; s += 8)
            WTb[(size_t)r * 65536 + (size_t)(j0 + ty + s) * 256 + (i0 + tx)] = f2bf(tt[tx][ty + s]);
    } else {
        int tg = (blockIdx.y * 8 + blockIdx.x) * 256 + t;       // 0..16383
        for (int e = tg; e < 73728; e += 16384) {
            float v = gW1[e];
            unsigned short b = f2bf(v);
            gW1b[e] = b;
            int k = e >> 13, n = (e >> 5) & 255, h = e & 31;
            g1Tb[(size_t)(k * 32 + h) * 256 + n] = b;
        }
    }
}

// -------------------- K1 (MFMA): d1[k][b][h] = silu'(a1) * upstream -----------
// Double-buffered L1 K-loop (round-3 proven form).
__global__ __launch_bounds__(256) void k_mlp(
    const float* __restrict__ z, const unsigned short* __restrict__ g1Tb,
    const float* __restrict__ gb1, const float* __restrict__ gW2,
    const float* __restrict__ gb2, const float* __restrict__ gW3,
    float* __restrict__ d1ws) {
    __shared__ uint4 As4[2][512]; // 2 x (128 rows x 32 k bf16); buf0 reused for h1/da2
    __shared__ uint4 Bw[1024];    // gW1^T block: 32 h x 256 n bf16, 8 chunk-regions
    __shared__ uint4 W2Ts4[128];  // W2^T [g][h] bf16 (fragment layout)
    __shared__ uint4 W2Ns4[128];  // W2 natural [h][g] bf16 (fragment layout)

    int t = threadIdx.x;
    int lane = t & 63;
    int w = t >> 6;
    int k = blockIdx.y;
    int b0 = blockIdx.x * 128;

    // ---- stage B (gW1^T) and W2 tiles ----
    const unsigned short* bsrc = g1Tb + (size_t)k * 8192;
    for (int e = t; e < 1024; e += 256) {
        int h = e >> 5;
        int rest = e & 31;
        int c = rest >> 2, qq = rest & 3;
        Bw[c * 128 + (h & 15) + 16 * qq + 64 * (h >> 4)] =
            *(const uint4*)(bsrc + (size_t)h * 256 + c * 32 + qq * 8);
    }
    const float* gw2 = gW2 + (size_t)k * 1024;
    unsigned short* w2t = (unsigned short*)W2Ts4;
    unsigned short* w2n = (unsigned short*)W2Ns4;
    for (int e = t; e < 1024; e += 256) {
        int n = e >> 5, kk = e & 31;
        int qq = kk >> 3, jj = kk & 7;
        int ci = (n & 15) + 16 * qq + 64 * (n >> 4);
        w2t[ci * 8 + jj] = f2bf(gw2[kk * 32 + n]);   // W2T[g=n][h=kk]
        w2n[ci * 8 + jj] = f2bf(gw2[n * 32 + kk]);   // W2N[h=n][g=kk]
    }

    int mq = t >> 2;
    int q = t & 3;
    int ci0 = (mq & 15) + 16 * q + 64 * (mq >> 4);   // pp=0; pp=1 -> +256

    // ---- layer-1 GEMM: acc1 = z_k @ gW1[k] (pipelined) ----
    f32x4 acc1[2][2];
    #pragma unroll
    for (int i = 0; i < 2; ++i)
        #pragma unroll
        for (int j = 0; j < 2; ++j) acc1[i][j] = (f32x4){0.f, 0.f, 0.f, 0.f};

    auto loadZ = [&](int c, float4 (&fa)[2][2]) {
        #pragma unroll
        for (int pp = 0; pp < 2; ++pp) {
            int m = mq + 64 * pp;
            const float* as = z + (size_t)(b0 + m) * ZDIM + k * 256 + c * 32 + q * 8;
            fa[pp][0] = *(const float4*)(as);
            fa[pp][1] = *(const float4*)(as + 4);
        }
    };
    auto storeA = [&](int buf, float4 (&fa)[2][2]) {
        #pragma unroll
        for (int pp = 0; pp < 2; ++pp)
            As4[buf][ci0 + 256 * pp] = pack8(fa[pp][0], fa[pp][1]);
    };

    {
        float4 fa[2][2];
        loadZ(0, fa);
        storeA(0, fa);
    }
    int cur = 0;
    for (int c = 0; c < 8; ++c) {
        __syncthreads();
        float4 fan[2][2];
        if (c < 7) loadZ(c + 1, fan);
        bf16x8 af[2], bfr[2];
        #pragma unroll
        for (int i = 0; i < 2; ++i) af[i] = __builtin_bit_cast(bf16x8, As4[cur][lane + (w * 2 + i) * 64]);
        #pragma unroll
        for (int j = 0; j < 2; ++j) bfr[j] = __builtin_bit_cast(bf16x8, Bw[c * 128 + lane + j * 64]);
        #pragma unroll
        for (int i = 0; i < 2; ++i)
            #pragma unroll
            for (int j = 0; j < 2; ++j)
                acc1[i][j] = __builtin_amdgcn_mfma_f32_16x16x32_bf16(af[i], bfr[j], acc1[i][j], 0, 0, 0);
        if (c < 7) storeA(cur ^ 1, fan);
        cur ^= 1;
    }

    // ---- bias + silu; keep silu'(a1); h1 -> LDS buf0 (chunk-swizzled bf16) ----
    int cq = lane >> 4;        // C-layout row quad
    int ci16 = lane & 15;      // C-layout col
    float b1v[2], b2v[2], g3v[2];
    #pragma unroll
    for (int j = 0; j < 2; ++j) {
        b1v[j] = gb1[k * 32 + j * 16 + ci16];
        b2v[j] = gb2[k * 32 + j * 16 + ci16];
        g3v[j] = gW3[k * 32 + j * 16 + ci16];
    }
    unsigned short* Hs = (unsigned short*)As4;
    float sp1[2][2][4];
    __syncthreads();           // all stage-1 As4 reads done
    #pragma unroll
    for (int i = 0; i < 2; ++i)
        #pragma unroll
        for (int j = 0; j < 2; ++j)
            #pragma unroll
            for (int r = 0; r < 4; ++r) {
                float a1 = acc1[i][j][r] + b1v[j];
                float s1 = 1.f / (1.f + __expf(-a1));
                sp1[i][j][r] = s1 * (1.f + a1 * (1.f - s1));
                int row = w * 32 + i * 16 + cq * 4 + r;
                int col = j * 16 + ci16;
                int chunk = (row & 15) + 16 * (col >> 3) + 64 * (row >> 4);
                Hs[chunk * 8 + (col & 7)] = f2bf(a1 * s1);
            }
    __syncthreads();

    // ---- layer-2: a2 = h1 @ W2 ----
    bf16x8 af2[2], wf[2];
    #pragma unroll
    for (int i = 0; i < 2; ++i) af2[i] = __builtin_bit_cast(bf16x8, As4[0][lane + (w * 2 + i) * 64]);
    #pragma unroll
    for (int j = 0; j < 2; ++j) wf[j] = __builtin_bit_cast(bf16x8, W2Ts4[lane + j * 64]);
    f32x4 acc2[2][2];
    #pragma unroll
    for (int i = 0; i < 2; ++i)
        #pragma unroll
        for (int j = 0; j < 2; ++j) {
            acc2[i][j] = (f32x4){0.f, 0.f, 0.f, 0.f};
            acc2[i][j] = __builtin_amdgcn_mfma_f32_16x16x32_bf16(af2[i], wf[j], acc2[i][j], 0, 0, 0);
        }

    // ---- da2 = gW3 * silu'(a2) -> LDS buf0 ----
    __syncthreads();           // h1 reads done
    #pragma unroll
    for (int i = 0; i < 2; ++i)
        #pragma unroll
        for (int j = 0; j < 2; ++j)
            #pragma unroll
            for (int r = 0; r < 4; ++r) {
                float a2 = acc2[i][j][r] + b2v[j];
                float s2 = 1.f / (1.f + __expf(-a2));
                float da2 = g3v[j] * s2 * (1.f + a2 * (1.f - s2));
                int row = w * 32 + i * 16 + cq * 4 + r;
                int col = j * 16 + ci16;
                int chunk = (row & 15) + 16 * (col >> 3) + 64 * (row >> 4);
                Hs[chunk * 8 + (col & 7)] = f2bf(da2);
            }
    __syncthreads();

    // ---- layer-3: dh1 = da2 @ W2^T; d1 = dh1 * silu'(a1) -> global ----
    bf16x8 af3[2], wg[2];
    #pragma unroll
    for (int i = 0; i < 2; ++i) af3[i] = __builtin_bit_cast(bf16x8, As4[0][lane + (w * 2 + i) * 64]);
    #pragma unroll
    for (int j = 0; j < 2; ++j) wg[j] = __builtin_bit_cast(bf16x8, W2Ns4[lane + j * 64]);
    #pragma unroll
    for (int i = 0; i < 2; ++i)
        #pragma unroll
        for (int j = 0; j < 2; ++j) {
            f32x4 a3 = (f32x4){0.f, 0.f, 0.f, 0.f};
            a3 = __builtin_amdgcn_mfma_f32_16x16x32_bf16(af3[i], wg[j], a3, 0, 0, 0);
            #pragma unroll
            for (int r = 0; r < 4; ++r) {
                int row = w * 32 + i * 16 + cq * 4 + r;
                int col = j * 16 + ci16;
                d1ws[((size_t)k * BATCH + b0 + row) * 32 + col] = a3[r] * sp1[i][j][r];
            }
        }
}

// ---- K2 (MFMA): out[:, 0:2048] = -(z8 @ W[7-k]  +  d1_k @ gW1[k]^T) -----------
// Grid (x=64 rows, y=16 cols): same-A col-WGs differ by 64 == 0 mod 8 XCDs.
// Double-buffered LDS pipeline (round-3 proven form).
__global__ __launch_bounds__(256) void k_gemm_lo(
    const float* __restrict__ z, const float* __restrict__ d1,
    const unsigned short* __restrict__ WTb, const unsigned short* __restrict__ gW1b,
    float* __restrict__ out) {
    __shared__ uint4 As4[2][512];   // 2 x (128 rows x 32 k bf16) = 16 KB
    __shared__ uint4 Bs4[2][512];   // 2 x (128 cols x 32 k bf16) = 16 KB

    int t = threadIdx.x;
    int lane = t & 63;
    int w = t >> 6;
    int wr = w >> 1, wc = w & 1;
    int b0 = blockIdx.x * 128;
    int n0 = blockIdx.y * 128;
    int k  = n0 >> 8;            // block index 0..7
    int jb = n0 & 255;           // 0 or 128

    const float* Amain = z + (size_t)b0 * ZDIM + 2048;
    const float* Aext  = d1 + ((size_t)k * BATCH + b0) * 32;
    const unsigned short* Bmain = WTb + (size_t)(7 - k) * 65536 + (size_t)jb * 256;
    const unsigned short* Bext  = gW1b + ((size_t)k * 256 + jb) * 32;

    int mq = t >> 2;
    int q  = t & 3;
    int ci0 = (mq & 15) + 16 * q + 64 * (mq >> 4);   // pp=0; pp=1 -> +256

    auto loadAB = [&](int c, float4 (&fa)[2][2], uint4 (&bu)[2]) {
        #pragma unroll
        for (int pp = 0; pp < 2; ++pp) {
            int m = mq + 64 * pp;
            const float* as = (c < 8) ? (Amain + (size_t)m * ZDIM + c * 32 + q * 8)
                                      : (Aext + (size_t)m * 32 + q * 8);
            fa[pp][0] = *(const float4*)(as);
            fa[pp][1] = *(const float4*)(as + 4);
            const unsigned short* bs = (c < 8) ? (Bmain + (size_t)m * 256 + c * 32 + q * 8)
                                               : (Bext + (size_t)m * 32 + q * 8);
            bu[pp] = *(const uint4*)(bs);
        }
    };
    auto storeAB = [&](int buf, float4 (&fa)[2][2], uint4 (&bu)[2]) {
        #pragma unroll
        for (int pp = 0; pp < 2; ++pp) {
            int idx = ci0 + 256 * pp;
            As4[buf][idx] = pack8(fa[pp][0], fa[pp][1]);
            Bs4[buf][idx] = bu[pp];
        }
    };

    f32x4 acc[4][4];
    #pragma unroll
    for (int i = 0; i < 4; ++i)
        #pragma unroll
        for (int j = 0; j < 4; ++j) acc[i][j] = (f32x4){0.f, 0.f, 0.f, 0.f};

    {
        float4 fa[2][2]; uint4 bu[2];
        loadAB(0, fa, bu);
        storeAB(0, fa, bu);
    }
    int cur = 0;
    for (int c = 0; c < 9; ++c) {
        __syncthreads();
        float4 fan[2][2]; uint4 bun[2];
        if (c < 8) loadAB(c + 1, fan, bun);
        bf16x8 af[4], bf[4];
        #pragma unroll
        for (int i = 0; i < 4; ++i) af[i] = __builtin_bit_cast(bf16x8, As4[cur][lane + (wr * 4 + i) * 64]);
        #pragma unroll
        for (int j = 0; j < 4; ++j) bf[j] = __builtin_bit_cast(bf16x8, Bs4[cur][lane + (wc * 4 + j) * 64]);
        #pragma unroll
        for (int i = 0; i < 4; ++i)
            #pragma unroll
            for (int j = 0; j < 4; ++j)
                acc[i][j] = __builtin_amdgcn_mfma_f32_16x16x32_bf16(af[i], bf[j], acc[i][j], 0, 0, 0);
        if (c < 8) storeAB(cur ^ 1, fan, bun);
        cur ^= 1;
    }

    int rquad = lane >> 4;
    int cidx  = lane & 15;
    #pragma unroll
    for (int i = 0; i < 4; ++i) {
        #pragma unroll
        for (int j = 0; j < 4; ++j) {
            float* o = out + (size_t)(b0 + wr * 64 + i * 16 + rquad * 4) * ZDIM
                     + (k * 256 + jb + wc * 64 + j * 16 + cidx);
            #pragma unroll
            for (int r = 0; r < 4; ++r)
                o[(size_t)r * ZDIM] = -acc[i][j][r];
        }
    }
}

// ---- K3 (MFMA, barrier-free): out[:, 2048:] -----------------------------------
// Each WAVE owns an independent 16-row x 64-col output strip over the FULL
// K=2080: A and B fragments are loaded DIRECTLY from global to registers
// (no LDS staging, zero __syncthreads). B (Wb, 512 KB) is L2-resident; A rows
// are read once per wave with full cacheline use (128 B/row per 32-k step).
// 512 WGs x 4 waves = 8 independent waves/CU -> pure TLP latency hiding,
// replacing the barrier-locked 1-step double buffer that stalled all prior
// hi variants. Register pipeline: next fragment loads issue before MFMAs.
// Same-A col-WGs differ by 128 in linear id == 0 mod 8 XCDs.
__global__ __launch_bounds__(256) void k_gemm_hi(
    const float* __restrict__ z, const float* __restrict__ d1,
    const unsigned short* __restrict__ Wb, const unsigned short* __restrict__ gW1b,
    float* __restrict__ out) {
    int t = threadIdx.x;
    int lane = t & 63;
    int w = t >> 6;              // wave -> rows b0 + w*16 .. +15
    int b0 = blockIdx.x * 64;    // batch row block
    int i0 = blockIdx.y * 64;    // hi output col block

    int rl = lane & 15;          // A row (within strip) / B col (within frag)
    int kq = lane >> 4;          // k-quarter (8 elements)

    const float* arow = z + (size_t)(b0 + w * 16 + rl) * ZDIM + kq * 8;
    const float* atail = d1 + ((size_t)8 * BATCH + b0 + w * 16 + rl) * 32 + kq * 8;

    f32x4 acc[4];
    #pragma unroll
    for (int j = 0; j < 4; ++j) acc[j] = (f32x4){0.f, 0.f, 0.f, 0.f};

    auto loadA = [&](int c, float4& x0, float4& x1) {
        const float* p = (c < 64) ? (arow + c * 32) : atail;
        x0 = *(const float4*)(p);
        x1 = *(const float4*)(p + 4);
    };
    auto loadB = [&](int c, uint4 (&bb)[4]) {
        if (c < 64) {
            int lag = c >> 3;
            int j0  = (c & 7) * 32;
            const unsigned short* base = Wb + (size_t)(7 - lag) * 65536 + j0 + kq * 8;
            #pragma unroll
            for (int j = 0; j < 4; ++j)
                bb[j] = *(const uint4*)(base + (size_t)(i0 + j * 16 + rl) * 256);
        } else {
            #pragma unroll
            for (int j = 0; j < 4; ++j)
                bb[j] = *(const uint4*)(gW1b + (size_t)(8 * 256 + i0 + j * 16 + rl) * 32 + kq * 8);
        }
    };

    float4 a0, a1;
    uint4 bb[4];
    loadA(0, a0, a1);
    loadB(0, bb);
    for (int c = 0; c < 65; ++c) {
        float4 na0, na1;
        uint4 nbb[4];
        if (c < 64) {
            loadA(c + 1, na0, na1);
            loadB(c + 1, nbb);
        }
        bf16x8 af = __builtin_bit_cast(bf16x8, pack8(a0, a1));
        #pragma unroll
        for (int j = 0; j < 4; ++j)
            acc[j] = __builtin_amdgcn_mfma_f32_16x16x32_bf16(
                af, __builtin_bit_cast(bf16x8, bb[j]), acc[j], 0, 0, 0);
        if (c < 64) {
            a0 = na0; a1 = na1;
            #pragma unroll
            for (int j = 0; j < 4; ++j) bb[j] = nbb[j];
        }
    }

    // C store: row = kq*4 + r within strip, col = rl within frag
    #pragma unroll
    for (int j = 0; j < 4; ++j) {
        float* o = out + (size_t)(b0 + w * 16 + kq * 4) * ZDIM + 2048 + i0 + j * 16 + rl;
        #pragma unroll
        for (int r = 0; r < 4; ++r)
            o[(size_t)r * ZDIM] = -acc[j][r];
    }
}

extern "C" void kernel_launch(void* const* d_in, const int* in_sizes, int n_in,
                              void* d_out, int out_size, void* d_ws, size_t ws_size,
                              hipStream_t stream) {
    const float* z   = (const float*)d_in[0];
    const float* gW1 = (const float*)d_in[1];
    const float* gb1 = (const float*)d_in[2];
    const float* gW2 = (const float*)d_in[3];
    const float* gb2 = (const float*)d_in[4];
    const float* gW3 = (const float*)d_in[5];
    // d_in[6] = gb3: constant, no grad
    const float* W   = (const float*)d_in[7];
    float* out = (float*)d_out;

    float* ws = (float*)d_ws;
    float*          d1ws = ws;                               // 2359296 f32 (9.4 MB)
    unsigned short* Wb   = (unsigned short*)(ws + 2359296);  // 524288 bf16
    unsigned short* WTb  = Wb + 524288;                      // 524288 bf16
    unsigned short* gW1b = WTb + 524288;                     // 73728 bf16
    unsigned short* g1Tb = gW1b + 73728;                     // 73728 bf16 (~11.8 MB total)

    k_pack<<<dim3(8, 8, 9), 256, 0, stream>>>(W, gW1, Wb, WTb, gW1b, g1Tb);
    k_mlp<<<dim3(64, 9), 256, 0, stream>>>(z, g1Tb, gb1, gW2, gb2, gW3, d1ws);
    k_gemm_lo<<<dim3(64, 16), 256, 0, stream>>>(z, d1ws, WTb, gW1b, out);
    k_gemm_hi<<<dim3(128, 4), 256, 0, stream>>>(z, d1ws, Wb, gW1b, out);
}

// Round 9
// 204.028 us; speedup vs baseline: 1.2747x; 1.2747x over previous
//
#include <hip/hip_runtime.h>
#include <hip/hip_bf16.h>
#include <math.h>

// Problem constants
#define BATCH 8192
#define NB 9
#define NN 256
#define PMAX 8
#define HID 32
#define ZDIM 2304   // NB*NN

typedef short bf16x8 __attribute__((ext_vector_type(8)));   // 8 bf16 in 4 VGPRs
typedef float f32x4 __attribute__((ext_vector_type(4)));    // MFMA accumulator

static __device__ inline unsigned short f2bf(float f) {
    __hip_bfloat16 h = __float2bfloat16(f);
    return *reinterpret_cast<unsigned short*>(&h);
}

static __device__ inline uint4 pack8(float4 a, float4 b) {
    uint4 u;
    u.x = (unsigned)f2bf(a.x) | ((unsigned)f2bf(a.y) << 16);
    u.y = (unsigned)f2bf(a.z) | ((unsigned)f2bf(a.w) << 16);
    u.z = (unsigned)f2bf(b.x) | ((unsigned)f2bf(b.y) << 16);
    u.w = (unsigned)f2bf(b.z) | ((unsigned)f2bf(b.w) << 16);
    return u;
}

// ---------------- K0: pack weights to bf16 ------------------------------------
// Wf: W in B-FRAGMENT order indexed by z-col chunk kc = (7-r)*8 + j/32:
//   Wf_uint4[(kc*16 + i/16)*64 + (i&15) + 16*((j>>3)&3)], elem j&7.
//   One wave's B-fragment load in k_gemm_hi = 64 lanes x 16B contiguous.
// WTb: W^T bf16 (for k_gemm_lo). g1Tb/gW1b as before.
__global__ __launch_bounds__(256) void k_pack(
    const float* __restrict__ W, const float* __restrict__ gW1,
    unsigned short* __restrict__ Wf, unsigned short* __restrict__ WTb,
    unsigned short* __restrict__ gW1b, unsigned short* __restrict__ g1Tb) {
    int r = blockIdx.z;
    int t = threadIdx.x;
    if (r < 8) {
        __shared__ float tt[32][33];
        int i0 = blockIdx.y * 32;
        int j0 = blockIdx.x * 32;
        int tx = t & 31;
        int ty = t >> 5;
        const float* src = W + (size_t)r * 65536;
        int kc2b = ((7 - r) << 3) + (j0 >> 5);   // kc for this j-block
        int j = j0 + tx;
        #pragma unroll
        for (int s = 0; s < 32; s += 8) {
            int i = i0 + ty + s;
            float v = src[(size_t)i * 256 + j];
            tt[ty + s][tx] = v;
            size_t widx = ((size_t)(kc2b * 16 + (i >> 4)) * 64
                           + ((i & 15) + 16 * ((j >> 3) & 3))) * 8 + (j & 7);
            Wf[widx] = f2bf(v);
        }
        __syncthreads();
        #pragma unroll
        for (int s = 0; s < 32; s += 8)
            WTb[(size_t)r * 65536 + (size_t)(j0 + ty + s) * 256 + (i0 + tx)] = f2bf(tt[tx][ty + s]);
    } else {
        int tg = (blockIdx.y * 8 + blockIdx.x) * 256 + t;       // 0..16383
        for (int e = tg; e < 73728; e += 16384) {
            float v = gW1[e];
            unsigned short b = f2bf(v);
            gW1b[e] = b;
            int k = e >> 13, n = (e >> 5) & 255, h = e & 31;
            g1Tb[(size_t)(k * 32 + h) * 256 + n] = b;
        }
    }
}

// -------------------- K1 (MFMA): d1[k][b][h] = silu'(a1) * upstream -----------
// Round-3 proven form + side-product zf: bf16 z in A-FRAGMENT order
//   zf_uint4[(rb*72 + kc)*64 + lane], rb = row/16, kc = k/32, lane = (row&15)+16*(k8).
// The packed uint4 already exists for LDS staging; one extra store per step.
__global__ __launch_bounds__(256) void k_mlp(
    const float* __restrict__ z, const unsigned short* __restrict__ g1Tb,
    const float* __restrict__ gb1, const float* __restrict__ gW2,
    const float* __restrict__ gb2, const float* __restrict__ gW3,
    float* __restrict__ d1ws, unsigned short* __restrict__ zf) {
    __shared__ uint4 As4[2][512]; // 2 x (128 rows x 32 k bf16); buf0 reused for h1/da2
    __shared__ uint4 Bw[1024];    // gW1^T block: 32 h x 256 n bf16, 8 chunk-regions
    __shared__ uint4 W2Ts4[128];  // W2^T [g][h] bf16 (fragment layout)
    __shared__ uint4 W2Ns4[128];  // W2 natural [h][g] bf16 (fragment layout)

    int t = threadIdx.x;
    int lane = t & 63;
    int w = t >> 6;
    int k = blockIdx.y;
    int b0 = blockIdx.x * 128;
    uint4* zfu = (uint4*)zf;
    int rb0 = b0 >> 4;

    // ---- stage B (gW1^T) and W2 tiles ----
    const unsigned short* bsrc = g1Tb + (size_t)k * 8192;
    for (int e = t; e < 1024; e += 256) {
        int h = e >> 5;
        int rest = e & 31;
        int c = rest >> 2, qq = rest & 3;
        Bw[c * 128 + (h & 15) + 16 * qq + 64 * (h >> 4)] =
            *(const uint4*)(bsrc + (size_t)h * 256 + c * 32 + qq * 8);
    }
    const float* gw2 = gW2 + (size_t)k * 1024;
    unsigned short* w2t = (unsigned short*)W2Ts4;
    unsigned short* w2n = (unsigned short*)W2Ns4;
    for (int e = t; e < 1024; e += 256) {
        int n = e >> 5, kk = e & 31;
        int qq = kk >> 3, jj = kk & 7;
        int ci = (n & 15) + 16 * qq + 64 * (n >> 4);
        w2t[ci * 8 + jj] = f2bf(gw2[kk * 32 + n]);   // W2T[g=n][h=kk]
        w2n[ci * 8 + jj] = f2bf(gw2[n * 32 + kk]);   // W2N[h=n][g=kk]
    }

    int mq = t >> 2;
    int q = t & 3;
    int ci0 = (mq & 15) + 16 * q + 64 * (mq >> 4);   // pp=0; pp=1 -> +256

    // ---- layer-1 GEMM: acc1 = z_k @ gW1[k] (pipelined) ----
    f32x4 acc1[2][2];
    #pragma unroll
    for (int i = 0; i < 2; ++i)
        #pragma unroll
        for (int j = 0; j < 2; ++j) acc1[i][j] = (f32x4){0.f, 0.f, 0.f, 0.f};

    auto loadZ = [&](int c, float4 (&fa)[2][2]) {
        #pragma unroll
        for (int pp = 0; pp < 2; ++pp) {
            int m = mq + 64 * pp;
            const float* as = z + (size_t)(b0 + m) * ZDIM + k * 256 + c * 32 + q * 8;
            fa[pp][0] = *(const float4*)(as);
            fa[pp][1] = *(const float4*)(as + 4);
        }
    };
    auto sinkZ = [&](int buf, int c, float4 (&fa)[2][2]) {
        int kc = k * 8 + c;
        #pragma unroll
        for (int pp = 0; pp < 2; ++pp) {
            uint4 pk = pack8(fa[pp][0], fa[pp][1]);
            int ci = ci0 + 256 * pp;
            As4[buf][ci] = pk;
            zfu[((size_t)(rb0 + (ci >> 6)) * 72 + kc) * 64 + (ci & 63)] = pk;
        }
    };

    {
        float4 fa[2][2];
        loadZ(0, fa);
        sinkZ(0, 0, fa);
    }
    int cur = 0;
    for (int c = 0; c < 8; ++c) {
        __syncthreads();
        float4 fan[2][2];
        if (c < 7) loadZ(c + 1, fan);
        bf16x8 af[2], bfr[2];
        #pragma unroll
        for (int i = 0; i < 2; ++i) af[i] = __builtin_bit_cast(bf16x8, As4[cur][lane + (w * 2 + i) * 64]);
        #pragma unroll
        for (int j = 0; j < 2; ++j) bfr[j] = __builtin_bit_cast(bf16x8, Bw[c * 128 + lane + j * 64]);
        #pragma unroll
        for (int i = 0; i < 2; ++i)
            #pragma unroll
            for (int j = 0; j < 2; ++j)
                acc1[i][j] = __builtin_amdgcn_mfma_f32_16x16x32_bf16(af[i], bfr[j], acc1[i][j], 0, 0, 0);
        if (c < 7) sinkZ(cur ^ 1, c + 1, fan);
        cur ^= 1;
    }

    // ---- bias + silu; keep silu'(a1); h1 -> LDS buf0 (chunk-swizzled bf16) ----
    int cq = lane >> 4;        // C-layout row quad
    int ci16 = lane & 15;      // C-layout col
    float b1v[2], b2v[2], g3v[2];
    #pragma unroll
    for (int j = 0; j < 2; ++j) {
        b1v[j] = gb1[k * 32 + j * 16 + ci16];
        b2v[j] = gb2[k * 32 + j * 16 + ci16];
        g3v[j] = gW3[k * 32 + j * 16 + ci16];
    }
    unsigned short* Hs = (unsigned short*)As4;
    float sp1[2][2][4];
    __syncthreads();           // all stage-1 As4 reads done
    #pragma unroll
    for (int i = 0; i < 2; ++i)
        #pragma unroll
        for (int j = 0; j < 2; ++j)
            #pragma unroll
            for (int r = 0; r < 4; ++r) {
                float a1 = acc1[i][j][r] + b1v[j];
                float s1 = 1.f / (1.f + __expf(-a1));
                sp1[i][j][r] = s1 * (1.f + a1 * (1.f - s1));
                int row = w * 32 + i * 16 + cq * 4 + r;
                int col = j * 16 + ci16;
                int chunk = (row & 15) + 16 * (col >> 3) + 64 * (row >> 4);
                Hs[chunk * 8 + (col & 7)] = f2bf(a1 * s1);
            }
    __syncthreads();

    // ---- layer-2: a2 = h1 @ W2 ----
    bf16x8 af2[2], wf[2];
    #pragma unroll
    for (int i = 0; i < 2; ++i) af2[i] = __builtin_bit_cast(bf16x8, As4[0][lane + (w * 2 + i) * 64]);
    #pragma unroll
    for (int j = 0; j < 2; ++j) wf[j] = __builtin_bit_cast(bf16x8, W2Ts4[lane + j * 64]);
    f32x4 acc2[2][2];
    #pragma unroll
    for (int i = 0; i < 2; ++i)
        #pragma unroll
        for (int j = 0; j < 2; ++j) {
            acc2[i][j] = (f32x4){0.f, 0.f, 0.f, 0.f};
            acc2[i][j] = __builtin_amdgcn_mfma_f32_16x16x32_bf16(af2[i], wf[j], acc2[i][j], 0, 0, 0);
        }

    // ---- da2 = gW3 * silu'(a2) -> LDS buf0 ----
    __syncthreads();           // h1 reads done
    #pragma unroll
    for (int i = 0; i < 2; ++i)
        #pragma unroll
        for (int j = 0; j < 2; ++j)
            #pragma unroll
            for (int r = 0; r < 4; ++r) {
                float a2 = acc2[i][j][r] + b2v[j];
                float s2 = 1.f / (1.f + __expf(-a2));
                float da2 = g3v[j] * s2 * (1.f + a2 * (1.f - s2));
                int row = w * 32 + i * 16 + cq * 4 + r;
                int col = j * 16 + ci16;
                int chunk = (row & 15) + 16 * (col >> 3) + 64 * (row >> 4);
                Hs[chunk * 8 + (col & 7)] = f2bf(da2);
            }
    __syncthreads();

    // ---- layer-3: dh1 = da2 @ W2^T; d1 = dh1 * silu'(a1) -> global ----
    bf16x8 af3[2], wg[2];
    #pragma unroll
    for (int i = 0; i < 2; ++i) af3[i] = __builtin_bit_cast(bf16x8, As4[0][lane + (w * 2 + i) * 64]);
    #pragma unroll
    for (int j = 0; j < 2; ++j) wg[j] = __builtin_bit_cast(bf16x8, W2Ns4[lane + j * 64]);
    #pragma unroll
    for (int i = 0; i < 2; ++i)
        #pragma unroll
        for (int j = 0; j < 2; ++j) {
            f32x4 a3 = (f32x4){0.f, 0.f, 0.f, 0.f};
            a3 = __builtin_amdgcn_mfma_f32_16x16x32_bf16(af3[i], wg[j], a3, 0, 0, 0);
            #pragma unroll
            for (int r = 0; r < 4; ++r) {
                int row = w * 32 + i * 16 + cq * 4 + r;
                int col = j * 16 + ci16;
                d1ws[((size_t)k * BATCH + b0 + row) * 32 + col] = a3[r] * sp1[i][j][r];
            }
        }
}

// ---- K2 (MFMA): out[:, 0:2048] = -(z8 @ W[7-k]  +  d1_k @ gW1[k]^T) -----------
// Round-3 proven pipeline; A main-steps now read zf (bf16 fragment layout,
// uint4 straight into LDS -> no pack8 in main loop).
__global__ __launch_bounds__(256) void k_gemm_lo(
    const unsigned short* __restrict__ zf, const float* __restrict__ d1,
    const unsigned short* __restrict__ WTb, const unsigned short* __restrict__ gW1b,
    float* __restrict__ out) {
    __shared__ uint4 As4[2][512];   // 2 x (128 rows x 32 k bf16) = 16 KB
    __shared__ uint4 Bs4[2][512];   // 2 x (128 cols x 32 k bf16) = 16 KB

    int t = threadIdx.x;
    int lane = t & 63;
    int w = t >> 6;
    int wr = w >> 1, wc = w & 1;
    int b0 = blockIdx.x * 128;
    int n0 = blockIdx.y * 128;
    int k  = n0 >> 8;            // block index 0..7
    int jb = n0 & 255;           // 0 or 128

    const uint4* zfu = (const uint4*)zf;
    int rb0 = b0 >> 4;
    const float* Aext  = d1 + ((size_t)k * BATCH + b0) * 32;
    const unsigned short* Bmain = WTb + (size_t)(7 - k) * 65536 + (size_t)jb * 256;
    const unsigned short* Bext  = gW1b + ((size_t)k * 256 + jb) * 32;

    int mq = t >> 2;
    int q  = t & 3;
    int ci0 = (mq & 15) + 16 * q + 64 * (mq >> 4);   // pp=0; pp=1 -> +256

    auto loadAB = [&](int c, uint4 (&au)[2], uint4 (&bu)[2]) {
        #pragma unroll
        for (int pp = 0; pp < 2; ++pp) {
            int m = mq + 64 * pp;
            int ci = ci0 + 256 * pp;
            if (c < 8) {
                au[pp] = zfu[((size_t)(rb0 + (ci >> 6)) * 72 + 64 + c) * 64 + (ci & 63)];
                bu[pp] = *(const uint4*)(Bmain + (size_t)m * 256 + c * 32 + q * 8);
            } else {
                const float* as = Aext + (size_t)m * 32 + q * 8;
                au[pp] = pack8(*(const float4*)(as), *(const float4*)(as + 4));
                bu[pp] = *(const uint4*)(Bext + (size_t)m * 32 + q * 8);
            }
        }
    };
    auto storeAB = [&](int buf, uint4 (&au)[2], uint4 (&bu)[2]) {
        #pragma unroll
        for (int pp = 0; pp < 2; ++pp) {
            int idx = ci0 + 256 * pp;
            As4[buf][idx] = au[pp];
            Bs4[buf][idx] = bu[pp];
        }
    };

    f32x4 acc[4][4];
    #pragma unroll
    for (int i = 0; i < 4; ++i)
        #pragma unroll
        for (int j = 0; j < 4; ++j) acc[i][j] = (f32x4){0.f, 0.f, 0.f, 0.f};

    {
        uint4 au[2], bu[2];
        loadAB(0, au, bu);
        storeAB(0, au, bu);
    }
    int cur = 0;
    for (int c = 0; c < 9; ++c) {
        __syncthreads();
        uint4 aun[2], bun[2];
        if (c < 8) loadAB(c + 1, aun, bun);
        bf16x8 af[4], bf[4];
        #pragma unroll
        for (int i = 0; i < 4; ++i) af[i] = __builtin_bit_cast(bf16x8, As4[cur][lane + (wr * 4 + i) * 64]);
        #pragma unroll
        for (int j = 0; j < 4; ++j) bf[j] = __builtin_bit_cast(bf16x8, Bs4[cur][lane + (wc * 4 + j) * 64]);
        #pragma unroll
        for (int i = 0; i < 4; ++i)
            #pragma unroll
            for (int j = 0; j < 4; ++j)
                acc[i][j] = __builtin_amdgcn_mfma_f32_16x16x32_bf16(af[i], bf[j], acc[i][j], 0, 0, 0);
        if (c < 8) storeAB(cur ^ 1, aun, bun);
        cur ^= 1;
    }

    int rquad = lane >> 4;
    int cidx  = lane & 15;
    #pragma unroll
    for (int i = 0; i < 4; ++i) {
        #pragma unroll
        for (int j = 0; j < 4; ++j) {
            float* o = out + (size_t)(b0 + wr * 64 + i * 16 + rquad * 4) * ZDIM
                     + (k * 256 + jb + wc * 64 + j * 16 + cidx);
            #pragma unroll
            for (int r = 0; r < 4; ++r)
                o[(size_t)r * ZDIM] = -acc[i][j][r];
        }
    }
}

// ---- K3 (MFMA, barrier-free + pre-swizzled): out[:, 2048:] --------------------
// Wave-independent 16x64 strips over full K=2080, zero LDS / zero barriers.
// A: 1 uint4/lane/step from zf (fragment order -> 1 KB coalesced per wave).
// B: 4 uint4/lane/step from Wf (fragment order, 1 MB L2-resident; shared by the
// WG's 4 waves via L1). No pack8 in the main loop.
// Same-A col-WGs differ by 128 in linear id == 0 mod 8 XCDs.
__global__ __launch_bounds__(256) void k_gemm_hi(
    const unsigned short* __restrict__ zf, const float* __restrict__ d1,
    const unsigned short* __restrict__ Wf, const unsigned short* __restrict__ gW1b,
    float* __restrict__ out) {
    int t = threadIdx.x;
    int lane = t & 63;
    int w = t >> 6;              // wave -> rows b0 + w*16 .. +15
    int b0 = blockIdx.x * 64;    // batch row block
    int i0 = blockIdx.y * 64;    // hi output col block

    int rl = lane & 15;          // A/B row-within-fragment
    int kq = lane >> 4;          // k-quarter (8 elements)

    int rb = (b0 >> 4) + w;      // zf rowblock for this wave's strip
    const uint4* Abase = (const uint4*)zf + (size_t)rb * 72 * 64 + lane;
    const uint4* Bbase = (const uint4*)Wf + (size_t)(i0 >> 4) * 64 + lane;
    const float* atail = d1 + ((size_t)8 * BATCH + b0 + w * 16 + rl) * 32 + kq * 8;

    f32x4 acc[4];
    #pragma unroll
    for (int j = 0; j < 4; ++j) acc[j] = (f32x4){0.f, 0.f, 0.f, 0.f};

    auto loadA = [&](int c, uint4& x) {
        if (c < 64) x = Abase[(size_t)c * 64];
        else x = pack8(*(const float4*)(atail), *(const float4*)(atail + 4));
    };
    auto loadB = [&](int c, uint4 (&bb)[4]) {
        if (c < 64) {
            #pragma unroll
            for (int j = 0; j < 4; ++j)
                bb[j] = Bbase[(size_t)c * 1024 + j * 64];
        } else {
            #pragma unroll
            for (int j = 0; j < 4; ++j)
                bb[j] = *(const uint4*)(gW1b + (size_t)(8 * 256 + i0 + j * 16 + rl) * 32 + kq * 8);
        }
    };

    uint4 a;
    uint4 bb[4];
    loadA(0, a);
    loadB(0, bb);
    for (int c = 0; c < 65; ++c) {
        uint4 na;
        uint4 nbb[4];
        if (c < 64) {
            loadA(c + 1, na);
            loadB(c + 1, nbb);
        }
        bf16x8 af = __builtin_bit_cast(bf16x8, a);
        #pragma unroll
        for (int j = 0; j < 4; ++j)
            acc[j] = __builtin_amdgcn_mfma_f32_16x16x32_bf16(
                af, __builtin_bit_cast(bf16x8, bb[j]), acc[j], 0, 0, 0);
        if (c < 64) {
            a = na;
            #pragma unroll
            for (int j = 0; j < 4; ++j) bb[j] = nbb[j];
        }
    }

    // C store: row = kq*4 + r within strip, col = j*16 + rl
    #pragma unroll
    for (int j = 0; j < 4; ++j) {
        float* o = out + (size_t)(b0 + w * 16 + kq * 4) * ZDIM + 2048 + i0 + j * 16 + rl;
        #pragma unroll
        for (int r = 0; r < 4; ++r)
            o[(size_t)r * ZDIM] = -acc[j][r];
    }
}

extern "C" void kernel_launch(void* const* d_in, const int* in_sizes, int n_in,
                              void* d_out, int out_size, void* d_ws, size_t ws_size,
                              hipStream_t stream) {
    const float* z   = (const float*)d_in[0];
    const float* gW1 = (const float*)d_in[1];
    const float* gb1 = (const float*)d_in[2];
    const float* gW2 = (const float*)d_in[3];
    const float* gb2 = (const float*)d_in[4];
    const float* gW3 = (const float*)d_in[5];
    // d_in[6] = gb3: constant, no grad
    const float* W   = (const float*)d_in[7];
    float* out = (float*)d_out;

    float* ws = (float*)d_ws;
    float*          d1ws = ws;                               // 2359296 f32 (9.4 MB)
    unsigned short* WTb  = (unsigned short*)(ws + 2359296);  // 524288 bf16
    unsigned short* Wf   = WTb + 524288;                     // 524288 bf16 (fragment order)
    unsigned short* gW1b = Wf + 524288;                      // 73728 bf16
    unsigned short* g1Tb = gW1b + 73728;                     // 73728 bf16
    unsigned short* zf   = g1Tb + 73728;                     // 18874368 bf16 (37.7 MB; ~49.6 MB total)

    k_pack<<<dim3(8, 8, 9), 256, 0, stream>>>(W, gW1, Wf, WTb, gW1b, g1Tb);
    k_mlp<<<dim3(64, 9), 256, 0, stream>>>(z, g1Tb, gb1, gW2, gb2, gW3, d1ws, zf);
    k_gemm_lo<<<dim3(64, 16), 256, 0, stream>>>(zf, d1ws, WTb, gW1b, out);
    k_gemm_hi<<<dim3(128, 4), 256, 0, stream>>>(zf, d1ws, Wf, gW1b, out);
}

// Round 10
// 203.134 us; speedup vs baseline: 1.2804x; 1.0044x over previous
//
#include <hip/hip_runtime.h>
#include <hip/hip_bf16.h>
#include <math.h>

// Problem constants
#define BATCH 8192
#define NB 9
#define NN 256
#define PMAX 8
#define HID 32
#define ZDIM 2304   // NB*NN

typedef short bf16x8 __attribute__((ext_vector_type(8)));   // 8 bf16 in 4 VGPRs
typedef float f32x4 __attribute__((ext_vector_type(4)));    // MFMA accumulator

static __device__ inline unsigned short f2bf(float f) {
    __hip_bfloat16 h = __float2bfloat16(f);
    return *reinterpret_cast<unsigned short*>(&h);
}

static __device__ inline uint4 pack8(float4 a, float4 b) {
    uint4 u;
    u.x = (unsigned)f2bf(a.x) | ((unsigned)f2bf(a.y) << 16);
    u.y = (unsigned)f2bf(a.z) | ((unsigned)f2bf(a.w) << 16);
    u.z = (unsigned)f2bf(b.x) | ((unsigned)f2bf(b.y) << 16);
    u.w = (unsigned)f2bf(b.z) | ((unsigned)f2bf(b.w) << 16);
    return u;
}

// ---------------- K0: pack weights to bf16 ------------------------------------
// Wf: W in B-FRAGMENT order by z-col chunk kc = (7-r)*8 + j/32 (r9 proven).
// WTb: W^T bf16 (for k_gemm_lo). g1Tb/gW1b as before.
__global__ __launch_bounds__(256) void k_pack(
    const float* __restrict__ W, const float* __restrict__ gW1,
    unsigned short* __restrict__ Wf, unsigned short* __restrict__ WTb,
    unsigned short* __restrict__ gW1b, unsigned short* __restrict__ g1Tb) {
    int r = blockIdx.z;
    int t = threadIdx.x;
    if (r < 8) {
        __shared__ float tt[32][33];
        int i0 = blockIdx.y * 32;
        int j0 = blockIdx.x * 32;
        int tx = t & 31;
        int ty = t >> 5;
        const float* src = W + (size_t)r * 65536;
        int kc2b = ((7 - r) << 3) + (j0 >> 5);   // kc for this j-block
        int j = j0 + tx;
        #pragma unroll
        for (int s = 0; s < 32; s += 8) {
            int i = i0 + ty + s;
            float v = src[(size_t)i * 256 + j];
            tt[ty + s][tx] = v;
            size_t widx = ((size_t)(kc2b * 16 + (i >> 4)) * 64
                           + ((i & 15) + 16 * ((j >> 3) & 3))) * 8 + (j & 7);
            Wf[widx] = f2bf(v);
        }
        __syncthreads();
        #pragma unroll
        for (int s = 0; s < 32; s += 8)
            WTb[(size_t)r * 65536 + (size_t)(j0 + ty + s) * 256 + (i0 + tx)] = f2bf(tt[tx][ty + s]);
    } else {
        int tg = (blockIdx.y * 8 + blockIdx.x) * 256 + t;       // 0..16383
        for (int e = tg; e < 73728; e += 16384) {
            float v = gW1[e];
            unsigned short b = f2bf(v);
            gW1b[e] = b;
            int k = e >> 13, n = (e >> 5) & 255, h = e & 31;
            g1Tb[(size_t)(k * 32 + h) * 256 + n] = b;
        }
    }
}

// -------------------- K1 (MFMA): d1f[k] = bf16(silu'(a1) * upstream) ----------
// 64-row WGs: grid (128,9) = 1152 WGs = 4.5 WG/CU = 18 waves/CU (2x r9 TLP).
// Side-products: zf (bf16 A-fragment z) and d1f (bf16 A-fragment d1, via the
// chunk-swizzled LDS tile which IS fragment order -> coalesced uint4 stores).
__global__ __launch_bounds__(256) void k_mlp(
    const float* __restrict__ z, const unsigned short* __restrict__ g1Tb,
    const float* __restrict__ gb1, const float* __restrict__ gW2,
    const float* __restrict__ gb2, const float* __restrict__ gW3,
    unsigned short* __restrict__ d1f, unsigned short* __restrict__ zf) {
    __shared__ uint4 As4[2][256]; // 2 x (64 rows x 32 k bf16); buf0 reused for h1/da2/d1
    __shared__ uint4 Bw[1024];    // gW1^T block: 32 h x 256 n bf16, 8 chunk-regions
    __shared__ uint4 W2Ts4[128];  // W2^T [g][h] bf16 (fragment layout)
    __shared__ uint4 W2Ns4[128];  // W2 natural [h][g] bf16 (fragment layout)

    int t = threadIdx.x;
    int lane = t & 63;
    int w = t >> 6;
    int k = blockIdx.y;
    int b0 = blockIdx.x * 64;
    uint4* zfu = (uint4*)zf;
    uint4* d1fu = (uint4*)d1f;
    int rb0 = b0 >> 4;

    // ---- stage B (gW1^T) and W2 tiles ----
    const unsigned short* bsrc = g1Tb + (size_t)k * 8192;
    for (int e = t; e < 1024; e += 256) {
        int h = e >> 5;
        int rest = e & 31;
        int c = rest >> 2, qq = rest & 3;
        Bw[c * 128 + (h & 15) + 16 * qq + 64 * (h >> 4)] =
            *(const uint4*)(bsrc + (size_t)h * 256 + c * 32 + qq * 8);
    }
    const float* gw2 = gW2 + (size_t)k * 1024;
    unsigned short* w2t = (unsigned short*)W2Ts4;
    unsigned short* w2n = (unsigned short*)W2Ns4;
    for (int e = t; e < 1024; e += 256) {
        int n = e >> 5, kk = e & 31;
        int qq = kk >> 3, jj = kk & 7;
        int ci = (n & 15) + 16 * qq + 64 * (n >> 4);
        w2t[ci * 8 + jj] = f2bf(gw2[kk * 32 + n]);   // W2T[g=n][h=kk]
        w2n[ci * 8 + jj] = f2bf(gw2[n * 32 + kk]);   // W2N[h=n][g=kk]
    }

    int mq = t >> 2;                                 // row 0..63
    int q = t & 3;
    int ci0 = (mq & 15) + 16 * q + 64 * (mq >> 4);   // 0..255

    // ---- layer-1 GEMM: acc1 = z_k @ gW1[k] (pipelined) ----
    f32x4 acc1[2];
    #pragma unroll
    for (int j = 0; j < 2; ++j) acc1[j] = (f32x4){0.f, 0.f, 0.f, 0.f};

    auto loadZ = [&](int c, float4 (&fa)[2]) {
        const float* as = z + (size_t)(b0 + mq) * ZDIM + k * 256 + c * 32 + q * 8;
        fa[0] = *(const float4*)(as);
        fa[1] = *(const float4*)(as + 4);
    };
    auto sinkZ = [&](int buf, int c, float4 (&fa)[2]) {
        uint4 pk = pack8(fa[0], fa[1]);
        As4[buf][ci0] = pk;
        zfu[((size_t)(rb0 + (ci0 >> 6)) * 72 + (k * 8 + c)) * 64 + (ci0 & 63)] = pk;
    };

    {
        float4 fa[2];
        loadZ(0, fa);
        sinkZ(0, 0, fa);
    }
    int cur = 0;
    for (int c = 0; c < 8; ++c) {
        __syncthreads();
        float4 fan[2];
        if (c < 7) loadZ(c + 1, fan);
        bf16x8 af = __builtin_bit_cast(bf16x8, As4[cur][w * 64 + lane]);
        bf16x8 bfr[2];
        #pragma unroll
        for (int j = 0; j < 2; ++j) bfr[j] = __builtin_bit_cast(bf16x8, Bw[c * 128 + lane + j * 64]);
        #pragma unroll
        for (int j = 0; j < 2; ++j)
            acc1[j] = __builtin_amdgcn_mfma_f32_16x16x32_bf16(af, bfr[j], acc1[j], 0, 0, 0);
        if (c < 7) sinkZ(cur ^ 1, c + 1, fan);
        cur ^= 1;
    }

    // ---- bias + silu; keep silu'(a1); h1 -> LDS buf0 (chunk-swizzled bf16) ----
    int cq = lane >> 4;        // C-layout row quad
    int ci16 = lane & 15;      // C-layout col
    float b1v[2], b2v[2], g3v[2];
    #pragma unroll
    for (int j = 0; j < 2; ++j) {
        b1v[j] = gb1[k * 32 + j * 16 + ci16];
        b2v[j] = gb2[k * 32 + j * 16 + ci16];
        g3v[j] = gW3[k * 32 + j * 16 + ci16];
    }
    unsigned short* Hs = (unsigned short*)As4;       // 64x32 bf16 tile = As4[0]
    float sp1[2][4];
    __syncthreads();           // all stage-1 As4 reads done
    #pragma unroll
    for (int j = 0; j < 2; ++j)
        #pragma unroll
        for (int r = 0; r < 4; ++r) {
            float a1 = acc1[j][r] + b1v[j];
            float s1 = 1.f / (1.f + __expf(-a1));
            sp1[j][r] = s1 * (1.f + a1 * (1.f - s1));
            int col = j * 16 + ci16;
            int chunk = ci16 + 16 * (col >> 3) + 64 * w;   // (row&15)=ci16? no
            // row = w*16 + cq*4 + r -> row&15 = cq*4+r
            chunk = (cq * 4 + r) + 16 * (col >> 3) + 64 * w;
            Hs[chunk * 8 + (col & 7)] = f2bf(a1 * s1);
        }
    __syncthreads();

    // ---- layer-2: a2 = h1 @ W2 ----
    bf16x8 af2 = __builtin_bit_cast(bf16x8, As4[0][w * 64 + lane]);
    bf16x8 wf[2];
    #pragma unroll
    for (int j = 0; j < 2; ++j) wf[j] = __builtin_bit_cast(bf16x8, W2Ts4[lane + j * 64]);
    f32x4 acc2[2];
    #pragma unroll
    for (int j = 0; j < 2; ++j) {
        acc2[j] = (f32x4){0.f, 0.f, 0.f, 0.f};
        acc2[j] = __builtin_amdgcn_mfma_f32_16x16x32_bf16(af2, wf[j], acc2[j], 0, 0, 0);
    }

    // ---- da2 = gW3 * silu'(a2) -> LDS buf0 ----
    __syncthreads();           // h1 reads done
    #pragma unroll
    for (int j = 0; j < 2; ++j)
        #pragma unroll
        for (int r = 0; r < 4; ++r) {
            float a2 = acc2[j][r] + b2v[j];
            float s2 = 1.f / (1.f + __expf(-a2));
            float da2 = g3v[j] * s2 * (1.f + a2 * (1.f - s2));
            int col = j * 16 + ci16;
            int chunk = (cq * 4 + r) + 16 * (col >> 3) + 64 * w;
            Hs[chunk * 8 + (col & 7)] = f2bf(da2);
        }
    __syncthreads();

    // ---- layer-3: dh1 = da2 @ W2^T; d1 = bf16(dh1 * silu'(a1)) -> LDS -> d1f --
    bf16x8 af3 = __builtin_bit_cast(bf16x8, As4[0][w * 64 + lane]);
    bf16x8 wg[2];
    #pragma unroll
    for (int j = 0; j < 2; ++j) wg[j] = __builtin_bit_cast(bf16x8, W2Ns4[lane + j * 64]);
    __syncthreads();           // all da2 reads (af3) in regs before overwrite
    #pragma unroll
    for (int j = 0; j < 2; ++j) {
        f32x4 a3 = (f32x4){0.f, 0.f, 0.f, 0.f};
        a3 = __builtin_amdgcn_mfma_f32_16x16x32_bf16(af3, wg[j], a3, 0, 0, 0);
        #pragma unroll
        for (int r = 0; r < 4; ++r) {
            int col = j * 16 + ci16;
            int chunk = (cq * 4 + r) + 16 * (col >> 3) + 64 * w;
            Hs[chunk * 8 + (col & 7)] = f2bf(a3[r] * sp1[j][r]);
        }
    }
    __syncthreads();
    // cooperative coalesced store: LDS chunk layout == A-fragment layout
    d1fu[((size_t)k * 512 + rb0 + (t >> 6)) * 64 + (t & 63)] = As4[0][t];
}

// ---- K2 (MFMA): out[:, 0:2048] = -(z8 @ W[7-k]  +  d1_k @ gW1[k]^T) -----------
// Round-3 proven pipeline; A main-steps from zf, tail from d1f (both bf16
// fragment layout, uint4 straight into LDS -> no pack8 anywhere).
__global__ __launch_bounds__(256) void k_gemm_lo(
    const unsigned short* __restrict__ zf, const unsigned short* __restrict__ d1f,
    const unsigned short* __restrict__ WTb, const unsigned short* __restrict__ gW1b,
    float* __restrict__ out) {
    __shared__ uint4 As4[2][512];   // 2 x (128 rows x 32 k bf16) = 16 KB
    __shared__ uint4 Bs4[2][512];   // 2 x (128 cols x 32 k bf16) = 16 KB

    int t = threadIdx.x;
    int lane = t & 63;
    int w = t >> 6;
    int wr = w >> 1, wc = w & 1;
    int b0 = blockIdx.x * 128;
    int n0 = blockIdx.y * 128;
    int k  = n0 >> 8;            // block index 0..7
    int jb = n0 & 255;           // 0 or 128

    const uint4* zfu  = (const uint4*)zf;
    const uint4* d1fu = (const uint4*)d1f;
    int rb0 = b0 >> 4;
    const unsigned short* Bmain = WTb + (size_t)(7 - k) * 65536 + (size_t)jb * 256;
    const unsigned short* Bext  = gW1b + ((size_t)k * 256 + jb) * 32;

    int mq = t >> 2;
    int q  = t & 3;
    int ci0 = (mq & 15) + 16 * q + 64 * (mq >> 4);   // pp=0; pp=1 -> +256

    auto loadAB = [&](int c, uint4 (&au)[2], uint4 (&bu)[2]) {
        #pragma unroll
        for (int pp = 0; pp < 2; ++pp) {
            int m = mq + 64 * pp;
            int ci = ci0 + 256 * pp;
            if (c < 8) {
                au[pp] = zfu[((size_t)(rb0 + (ci >> 6)) * 72 + 64 + c) * 64 + (ci & 63)];
                bu[pp] = *(const uint4*)(Bmain + (size_t)m * 256 + c * 32 + q * 8);
            } else {
                au[pp] = d1fu[((size_t)k * 512 + rb0 + (ci >> 6)) * 64 + (ci & 63)];
                bu[pp] = *(const uint4*)(Bext + (size_t)m * 32 + q * 8);
            }
        }
    };
    auto storeAB = [&](int buf, uint4 (&au)[2], uint4 (&bu)[2]) {
        #pragma unroll
        for (int pp = 0; pp < 2; ++pp) {
            int idx = ci0 + 256 * pp;
            As4[buf][idx] = au[pp];
            Bs4[buf][idx] = bu[pp];
        }
    };

    f32x4 acc[4][4];
    #pragma unroll
    for (int i = 0; i < 4; ++i)
        #pragma unroll
        for (int j = 0; j < 4; ++j) acc[i][j] = (f32x4){0.f, 0.f, 0.f, 0.f};

    {
        uint4 au[2], bu[2];
        loadAB(0, au, bu);
        storeAB(0, au, bu);
    }
    int cur = 0;
    for (int c = 0; c < 9; ++c) {
        __syncthreads();
        uint4 aun[2], bun[2];
        if (c < 8) loadAB(c + 1, aun, bun);
        bf16x8 af[4], bf[4];
        #pragma unroll
        for (int i = 0; i < 4; ++i) af[i] = __builtin_bit_cast(bf16x8, As4[cur][lane + (wr * 4 + i) * 64]);
        #pragma unroll
        for (int j = 0; j < 4; ++j) bf[j] = __builtin_bit_cast(bf16x8, Bs4[cur][lane + (wc * 4 + j) * 64]);
        #pragma unroll
        for (int i = 0; i < 4; ++i)
            #pragma unroll
            for (int j = 0; j < 4; ++j)
                acc[i][j] = __builtin_amdgcn_mfma_f32_16x16x32_bf16(af[i], bf[j], acc[i][j], 0, 0, 0);
        if (c < 8) storeAB(cur ^ 1, aun, bun);
        cur ^= 1;
    }

    int rquad = lane >> 4;
    int cidx  = lane & 15;
    #pragma unroll
    for (int i = 0; i < 4; ++i) {
        #pragma unroll
        for (int j = 0; j < 4; ++j) {
            float* o = out + (size_t)(b0 + wr * 64 + i * 16 + rquad * 4) * ZDIM
                     + (k * 256 + jb + wc * 64 + j * 16 + cidx);
            #pragma unroll
            for (int r = 0; r < 4; ++r)
                o[(size_t)r * ZDIM] = -acc[i][j][r];
        }
    }
}

// ---- K3 (MFMA, barrier-free + pre-swizzled): out[:, 2048:] --------------------
// Wave-independent 16x64 strips over full K=2080, zero LDS / zero barriers.
// A: 1 uint4/lane/step from zf; tail from d1f. B: 4 uint4/lane/step from Wf.
// All fragment-ordered -> every load is one 1 KB coalesced wave transaction.
__global__ __launch_bounds__(256) void k_gemm_hi(
    const unsigned short* __restrict__ zf, const unsigned short* __restrict__ d1f,
    const unsigned short* __restrict__ Wf, const unsigned short* __restrict__ gW1b,
    float* __restrict__ out) {
    int t = threadIdx.x;
    int lane = t & 63;
    int w = t >> 6;              // wave -> rows b0 + w*16 .. +15
    int b0 = blockIdx.x * 64;    // batch row block
    int i0 = blockIdx.y * 64;    // hi output col block

    int rl = lane & 15;          // A/B row-within-fragment
    int kq = lane >> 4;          // k-quarter (8 elements)

    int rb = (b0 >> 4) + w;      // zf rowblock for this wave's strip
    const uint4* Abase = (const uint4*)zf + (size_t)rb * 72 * 64 + lane;
    const uint4* Atail = (const uint4*)d1f + ((size_t)8 * 512 + rb) * 64 + lane;
    const uint4* Bbase = (const uint4*)Wf + (size_t)(i0 >> 4) * 64 + lane;

    f32x4 acc[4];
    #pragma unroll
    for (int j = 0; j < 4; ++j) acc[j] = (f32x4){0.f, 0.f, 0.f, 0.f};

    auto loadA = [&](int c, uint4& x) {
        x = (c < 64) ? Abase[(size_t)c * 64] : Atail[0];
    };
    auto loadB = [&](int c, uint4 (&bb)[4]) {
        if (c < 64) {
            #pragma unroll
            for (int j = 0; j < 4; ++j)
                bb[j] = Bbase[(size_t)c * 1024 + j * 64];
        } else {
            #pragma unroll
            for (int j = 0; j < 4; ++j)
                bb[j] = *(const uint4*)(gW1b + (size_t)(8 * 256 + i0 + j * 16 + rl) * 32 + kq * 8);
        }
    };

    uint4 a;
    uint4 bb[4];
    loadA(0, a);
    loadB(0, bb);
    for (int c = 0; c < 65; ++c) {
        uint4 na;
        uint4 nbb[4];
        if (c < 64) {
            loadA(c + 1, na);
            loadB(c + 1, nbb);
        }
        bf16x8 af = __builtin_bit_cast(bf16x8, a);
        #pragma unroll
        for (int j = 0; j < 4; ++j)
            acc[j] = __builtin_amdgcn_mfma_f32_16x16x32_bf16(
                af, __builtin_bit_cast(bf16x8, bb[j]), acc[j], 0, 0, 0);
        if (c < 64) {
            a = na;
            #pragma unroll
            for (int j = 0; j < 4; ++j) bb[j] = nbb[j];
        }
    }

    // C store: row = kq*4 + r within strip, col = j*16 + rl
    #pragma unroll
    for (int j = 0; j < 4; ++j) {
        float* o = out + (size_t)(b0 + w * 16 + kq * 4) * ZDIM + 2048 + i0 + j * 16 + rl;
        #pragma unroll
        for (int r = 0; r < 4; ++r)
            o[(size_t)r * ZDIM] = -acc[j][r];
    }
}

extern "C" void kernel_launch(void* const* d_in, const int* in_sizes, int n_in,
                              void* d_out, int out_size, void* d_ws, size_t ws_size,
                              hipStream_t stream) {
    const float* z   = (const float*)d_in[0];
    const float* gW1 = (const float*)d_in[1];
    const float* gb1 = (const float*)d_in[2];
    const float* gW2 = (const float*)d_in[3];
    const float* gb2 = (const float*)d_in[4];
    const float* gW3 = (const float*)d_in[5];
    // d_in[6] = gb3: constant, no grad
    const float* W   = (const float*)d_in[7];
    float* out = (float*)d_out;

    unsigned short* d1f  = (unsigned short*)d_ws;            // 2359296 bf16 (4.7 MB, fragment order)
    unsigned short* WTb  = d1f + 2359296;                    // 524288 bf16
    unsigned short* Wf   = WTb + 524288;                     // 524288 bf16 (fragment order)
    unsigned short* gW1b = Wf + 524288;                      // 73728 bf16
    unsigned short* g1Tb = gW1b + 73728;                     // 73728 bf16
    unsigned short* zf   = g1Tb + 73728;                     // 18874368 bf16 (37.7 MB; ~45 MB total)

    k_pack<<<dim3(8, 8, 9), 256, 0, stream>>>(W, gW1, Wf, WTb, gW1b, g1Tb);
    k_mlp<<<dim3(128, 9), 256, 0, stream>>>(z, g1Tb, gb1, gW2, gb2, gW3, d1f, zf);
    k_gemm_lo<<<dim3(64, 16), 256, 0, stream>>>(zf, d1f, WTb, gW1b, out);
    k_gemm_hi<<<dim3(128, 4), 256, 0, stream>>>(zf, d1f, Wf, gW1b, out);
}